// Round 2
// baseline (202.854 us; speedup 1.0000x reference)
//
#include <hip/hip_runtime.h>
#include <hip/hip_bf16.h>

#define NVOX 4096      // 16*16*16
#define C    128
#define HID  512
#define EPSF 1e-6f

// ---------------- Kernel 1: rmsnorm(x)*w1 -> q,k,v (fp32) ----------------
__global__ __launch_bounds__(128) void k_norm_qkv(
    const float* __restrict__ x, const float* __restrict__ nw,
    const float* __restrict__ wq, const float* __restrict__ wk, const float* __restrict__ wv,
    float* __restrict__ q, float* __restrict__ k, float* __restrict__ v)
{
    int row = blockIdx.x, t = threadIdx.x;
    __shared__ float hs[C];
    __shared__ float red[C];
    float xv = x[row * C + t];
    red[t] = xv * xv; __syncthreads();
    for (int s = 64; s > 0; s >>= 1) { if (t < s) red[t] += red[t + s]; __syncthreads(); }
    float scale = rsqrtf(red[0] * (1.0f / C) + EPSF);
    hs[t] = xv * scale * nw[t];
    __syncthreads();
    float aq = 0.f, ak = 0.f, av = 0.f;
    for (int j = 0; j < C; j++) {
        float hj = hs[j];
        aq = fmaf(hj, wq[j * C + t], aq);
        ak = fmaf(hj, wk[j * C + t], ak);
        av = fmaf(hj, wv[j * C + t], av);
    }
    q[row * C + t] = aq; k[row * C + t] = ak; v[row * C + t] = av;
}

// ---------------- Kernel 2: local-window attention ----------------
// grid = 4096 voxels, block = 256 (4 waves, one per head)
__global__ __launch_bounds__(256) void k_attn(
    const float* __restrict__ q, const float* __restrict__ k, const float* __restrict__ v,
    float* __restrict__ o)
{
    int vox = blockIdx.x;
    int w0 = vox & 15, h0 = (vox >> 4) & 15, d0 = vox >> 8;
    int head = threadIdx.x >> 6;
    int lane = threadIdx.x & 63;

    __shared__ float qs[C];
    __shared__ float ps[4][128];
    __shared__ int   ns[128];

    if (threadIdx.x < C) qs[threadIdx.x] = q[vox * C + threadIdx.x];
    if (head == 0) { ns[lane] = -1; ns[lane + 64] = -1; }
    __syncthreads();

    const float inv_sqrt_hd = 0.17677669529663687f; // 1/sqrt(32)
    float sc[2] = { -1e30f, -1e30f };
    for (int r = 0; r < 2; r++) {
        int kk = lane + 64 * r;
        if (kk < 125) {
            int dd = kk / 25 - 2;
            int dh = (kk / 5) % 5 - 2;
            int dw = kk % 5 - 2;
            int nd = d0 + dd, nh = h0 + dh, nw_ = w0 + dw;
            if ((unsigned)nd < 16u && (unsigned)nh < 16u && (unsigned)nw_ < 16u) {
                int nvox = (nd << 8) | (nh << 4) | nw_;
                if (head == 0) ns[kk] = nvox;
                const float* kp = k + (size_t)nvox * C + head * 32;
                float acc = 0.f;
                #pragma unroll
                for (int e = 0; e < 32; e++) acc = fmaf(qs[head * 32 + e], kp[e], acc);
                sc[r] = acc * inv_sqrt_hd;
            }
        }
    }
    // wave softmax over <=125 positions (invalid excluded; exact vs ref since exp(-1e9-m)->0)
    float m = fmaxf(sc[0], sc[1]);
    for (int off = 32; off; off >>= 1) m = fmaxf(m, __shfl_xor(m, off));
    float e0 = (sc[0] > -1e29f) ? __expf(sc[0] - m) : 0.f;
    float e1 = (sc[1] > -1e29f) ? __expf(sc[1] - m) : 0.f;
    float s = e0 + e1;
    for (int off = 32; off; off >>= 1) s += __shfl_xor(s, off);
    float invs = 1.0f / s;
    ps[head][lane] = e0 * invs;
    ps[head][lane + 64] = e1 * invs;
    __syncthreads();

    // output: 32 channels per head; lanes 0..31 do positions [0,64), lanes 32..63 do [64,125)
    int e = lane & 31;
    int half = lane >> 5;
    float acc = 0.f;
    int kk0 = half ? 64 : 0, kk1 = half ? 125 : 64;
    for (int kk = kk0; kk < kk1; kk++) {
        int nv = ns[kk];
        if (nv >= 0) acc = fmaf(ps[head][kk], v[(size_t)nv * C + head * 32 + e], acc);
    }
    acc += __shfl_xor(acc, 32);
    if (half == 0) o[vox * C + head * 32 + e] = acc;
}

// ---------------- Kernel 3: xres = x + rmsnorm(o@wo)*attn_norm_w ----------------
__global__ __launch_bounds__(128) void k_attnout(
    const float* __restrict__ o, const float* __restrict__ wo,
    const float* __restrict__ anw, const float* __restrict__ x,
    float* __restrict__ xres)
{
    int row = blockIdx.x, t = threadIdx.x;
    __shared__ float os[C];
    __shared__ float red[C];
    os[t] = o[row * C + t]; __syncthreads();
    float acc = 0.f;
    for (int j = 0; j < C; j++) acc = fmaf(os[j], wo[j * C + t], acc);
    red[t] = acc * acc; __syncthreads();
    for (int s = 64; s > 0; s >>= 1) { if (t < s) red[t] += red[t + s]; __syncthreads(); }
    float scale = rsqrtf(red[0] * (1.0f / C) + EPSF);
    xres[row * C + t] = x[row * C + t] + acc * scale * anw[t];
}

// ---------------- Kernel 4: h2 = rmsnorm(xres)*n2; gu = silu(h2@gate)*(h2@up) ----------------
__global__ __launch_bounds__(128) void k_ffn1(
    const float* __restrict__ xres, const float* __restrict__ n2w,
    const float* __restrict__ gw, const float* __restrict__ uw,
    float* __restrict__ gu)
{
    int row = blockIdx.x, t = threadIdx.x;
    __shared__ float hs[C];
    __shared__ float red[C];
    float xv = xres[row * C + t];
    red[t] = xv * xv; __syncthreads();
    for (int s = 64; s > 0; s >>= 1) { if (t < s) red[t] += red[t + s]; __syncthreads(); }
    float scale = rsqrtf(red[0] * (1.0f / C) + EPSF);
    hs[t] = xv * scale * n2w[t];
    __syncthreads();
    for (int c = t; c < HID; c += C) {
        float g = 0.f, u = 0.f;
        for (int j = 0; j < C; j++) {
            float hj = hs[j];
            g = fmaf(hj, gw[j * HID + c], g);
            u = fmaf(hj, uw[j * HID + c], u);
        }
        float sg = g / (1.0f + __expf(-g));   // silu
        gu[row * HID + c] = sg * u;
    }
}

// ---------------- Kernel 5: out = xres + gu@down ----------------
__global__ __launch_bounds__(128) void k_ffn2(
    const float* __restrict__ gu, const float* __restrict__ dw,
    const float* __restrict__ xres, float* __restrict__ out)
{
    int row = blockIdx.x, t = threadIdx.x;
    __shared__ float gs[HID];
    for (int c = t; c < HID; c += C) gs[c] = gu[row * HID + c];
    __syncthreads();
    float acc = 0.f;
    for (int j = 0; j < HID; j++) acc = fmaf(gs[j], dw[j * C + t], acc);
    out[row * C + t] = xres[row * C + t] + acc;
}

extern "C" void kernel_launch(void* const* d_in, const int* in_sizes, int n_in,
                              void* d_out, int out_size, void* d_ws, size_t ws_size,
                              hipStream_t stream)
{
    const float* x   = (const float*)d_in[0];
    const float* n1  = (const float*)d_in[1];
    const float* anw = (const float*)d_in[2];
    const float* n2  = (const float*)d_in[3];
    const float* wq  = (const float*)d_in[4];
    const float* wk  = (const float*)d_in[5];
    const float* wv  = (const float*)d_in[6];
    const float* wo  = (const float*)d_in[7];
    const float* gw  = (const float*)d_in[8];
    const float* uw  = (const float*)d_in[9];
    const float* dw  = (const float*)d_in[10];
    float* out = (float*)d_out;

    float* ws = (float*)d_ws;
    const size_t N = (size_t)NVOX * C;
    float* q    = ws;
    float* k    = ws + N;
    float* v    = ws + 2 * N;
    float* o    = ws + 3 * N;
    float* xres = ws + 4 * N;
    float* gu   = ws + 5 * N;   // NVOX*HID = 4N floats

    k_norm_qkv<<<NVOX, 128, 0, stream>>>(x, n1, wq, wk, wv, q, k, v);
    k_attn   <<<NVOX, 256, 0, stream>>>(q, k, v, o);
    k_attnout<<<NVOX, 128, 0, stream>>>(o, wo, anw, x, xres);
    k_ffn1   <<<NVOX, 128, 0, stream>>>(xres, n2, gw, uw, gu);
    k_ffn2   <<<NVOX, 128, 0, stream>>>(gu, dw, xres, out);
}

// Round 3
// 181.333 us; speedup vs baseline: 1.1187x; 1.1187x over previous
//
#include <hip/hip_runtime.h>
#include <hip/hip_bf16.h>

#define NVOX 4096      // 16*16*16
#define C    128
#define HID  512
#define EPSF 1e-6f
#define R    16        // rows per block tile

// ---------------- Kernel 1: rmsnorm(x)*n1 -> q,k,v  (R=16 rows/block) ----------------
// 384 threads: mat = t>>7 (wq/wk/wv), col = t&127. Weight reads amortized 16x.
__global__ __launch_bounds__(384) void k_norm_qkv(
    const float* __restrict__ x, const float* __restrict__ nw,
    const float* __restrict__ wq, const float* __restrict__ wk, const float* __restrict__ wv,
    float* __restrict__ q, float* __restrict__ k, float* __restrict__ v)
{
    __shared__ float xs[R][C];
    __shared__ float red[R][8];
    __shared__ float scl[R];
    const int r0 = blockIdx.x * R;
    const int t = threadIdx.x;

    // stage x tile (2048 floats = 512 float4)
    for (int vi = t; vi < 512; vi += 384) {
        int r = vi >> 5, jc = (vi & 31) << 2;
        *(float4*)&xs[r][jc] = *(const float4*)&x[(size_t)(r0 + r) * C + jc];
    }
    __syncthreads();
    if (t < 128) {
        int r = t >> 3, seg = t & 7;
        float s = 0.f;
        #pragma unroll
        for (int i = 0; i < 16; i++) { float xv = xs[r][seg * 16 + i]; s = fmaf(xv, xv, s); }
        red[r][seg] = s;
    }
    __syncthreads();
    if (t < R) {
        float s = 0.f;
        #pragma unroll
        for (int i = 0; i < 8; i++) s += red[t][i];
        scl[t] = rsqrtf(s * (1.0f / C) + EPSF);
    }
    __syncthreads();
    for (int vi = t; vi < 512; vi += 384) {
        int r = vi >> 5, jc = (vi & 31) << 2;
        float4 val = *(float4*)&xs[r][jc];
        float4 w4 = *(const float4*)&nw[jc];
        float sc = scl[r];
        val.x *= sc * w4.x; val.y *= sc * w4.y; val.z *= sc * w4.z; val.w *= sc * w4.w;
        *(float4*)&xs[r][jc] = val;
    }
    __syncthreads();

    const int m = t >> 7;            // 0,1,2 -> q,k,v (uniform per 2-wave group)
    const int c = t & 127;
    const float* __restrict__ w = (m == 0) ? wq : (m == 1) ? wk : wv;
    float* __restrict__ outp     = (m == 0) ? q  : (m == 1) ? k  : v;
    float acc[R] = {};
    for (int j = 0; j < C; j++) {
        float wj = w[j * C + c];
        #pragma unroll
        for (int r = 0; r < R; r++) acc[r] = fmaf(xs[r][j], wj, acc[r]);
    }
    for (int r = 0; r < R; r++) outp[(size_t)(r0 + r) * C + c] = acc[r];
}

// ---------------- Kernel 2: local-window attention (unchanged) ----------------
__global__ __launch_bounds__(256) void k_attn(
    const float* __restrict__ q, const float* __restrict__ k, const float* __restrict__ v,
    float* __restrict__ o)
{
    int vox = blockIdx.x;
    int w0 = vox & 15, h0 = (vox >> 4) & 15, d0 = vox >> 8;
    int head = threadIdx.x >> 6;
    int lane = threadIdx.x & 63;

    __shared__ float qs[C];
    __shared__ float ps[4][128];
    __shared__ int   ns[128];

    if (threadIdx.x < C) qs[threadIdx.x] = q[vox * C + threadIdx.x];
    if (head == 0) { ns[lane] = -1; ns[lane + 64] = -1; }
    __syncthreads();

    const float inv_sqrt_hd = 0.17677669529663687f; // 1/sqrt(32)
    float sc[2] = { -1e30f, -1e30f };
    for (int r = 0; r < 2; r++) {
        int kk = lane + 64 * r;
        if (kk < 125) {
            int dd = kk / 25 - 2;
            int dh = (kk / 5) % 5 - 2;
            int dw = kk % 5 - 2;
            int nd = d0 + dd, nh = h0 + dh, nw_ = w0 + dw;
            if ((unsigned)nd < 16u && (unsigned)nh < 16u && (unsigned)nw_ < 16u) {
                int nvox = (nd << 8) | (nh << 4) | nw_;
                if (head == 0) ns[kk] = nvox;
                const float* kp = k + (size_t)nvox * C + head * 32;
                float acc = 0.f;
                #pragma unroll
                for (int e = 0; e < 32; e++) acc = fmaf(qs[head * 32 + e], kp[e], acc);
                sc[r] = acc * inv_sqrt_hd;
            }
        }
    }
    float m = fmaxf(sc[0], sc[1]);
    for (int off = 32; off; off >>= 1) m = fmaxf(m, __shfl_xor(m, off));
    float e0 = (sc[0] > -1e29f) ? __expf(sc[0] - m) : 0.f;
    float e1 = (sc[1] > -1e29f) ? __expf(sc[1] - m) : 0.f;
    float s = e0 + e1;
    for (int off = 32; off; off >>= 1) s += __shfl_xor(s, off);
    float invs = 1.0f / s;
    ps[head][lane] = e0 * invs;
    ps[head][lane + 64] = e1 * invs;
    __syncthreads();

    int e = lane & 31;
    int half = lane >> 5;
    float acc = 0.f;
    int kk0 = half ? 64 : 0, kk1 = half ? 125 : 64;
    for (int kk = kk0; kk < kk1; kk++) {
        int nv = ns[kk];
        if (nv >= 0) acc = fmaf(ps[head][kk], v[(size_t)nv * C + head * 32 + e], acc);
    }
    acc += __shfl_xor(acc, 32);
    if (half == 0) o[vox * C + head * 32 + e] = acc;
}

// ---------------- Kernel 3: xres = x + rmsnorm(o@wo)*anw  (R=16) ----------------
__global__ __launch_bounds__(256) void k_attnout(
    const float* __restrict__ o, const float* __restrict__ wo,
    const float* __restrict__ anw, const float* __restrict__ x,
    float* __restrict__ xres)
{
    __shared__ float os[R][C];
    __shared__ float ybuf[2][R][C];
    __shared__ float red[R][8];
    __shared__ float scl[R];
    const int r0 = blockIdx.x * R;
    const int t = threadIdx.x;

    for (int vi = t; vi < 512; vi += 256) {
        int r = vi >> 5, jc = (vi & 31) << 2;
        *(float4*)&os[r][jc] = *(const float4*)&o[(size_t)(r0 + r) * C + jc];
    }
    __syncthreads();

    const int c = t & 127, kh = t >> 7;
    float acc[R] = {};
    for (int j = kh * 64; j < kh * 64 + 64; j++) {
        float wj = wo[j * C + c];
        #pragma unroll
        for (int r = 0; r < R; r++) acc[r] = fmaf(os[r][j], wj, acc[r]);
    }
    #pragma unroll
    for (int r = 0; r < R; r++) ybuf[kh][r][c] = acc[r];
    __syncthreads();
    if (t < 128) {
        #pragma unroll
        for (int r = 0; r < R; r++) ybuf[0][r][t] += ybuf[1][r][t];
    }
    __syncthreads();
    if (t < 128) {
        int r = t >> 3, seg = t & 7;
        float s = 0.f;
        #pragma unroll
        for (int i = 0; i < 16; i++) { float yv = ybuf[0][r][seg * 16 + i]; s = fmaf(yv, yv, s); }
        red[r][seg] = s;
    }
    __syncthreads();
    if (t < R) {
        float s = 0.f;
        #pragma unroll
        for (int i = 0; i < 8; i++) s += red[t][i];
        scl[t] = rsqrtf(s * (1.0f / C) + EPSF);
    }
    __syncthreads();
    if (t < 128) {
        float aw = anw[t];
        for (int r = 0; r < R; r++) {
            size_t idx = (size_t)(r0 + r) * C + t;
            xres[idx] = x[idx] + ybuf[0][r][t] * scl[r] * aw;
        }
    }
}

// ---------------- Kernel 4: h2=rmsnorm(xres)*n2; gu = silu(h2@gw)*(h2@uw)  (R=16) ----------------
// grid (256, 2); thread owns one col (both gate and up) -> no exchange needed
__global__ __launch_bounds__(256) void k_ffn1(
    const float* __restrict__ xres, const float* __restrict__ n2w,
    const float* __restrict__ gw, const float* __restrict__ uw,
    float* __restrict__ gu)
{
    __shared__ float hs[R][C];
    __shared__ float red[R][8];
    __shared__ float scl[R];
    const int r0 = blockIdx.x * R;
    const int t = threadIdx.x;

    for (int vi = t; vi < 512; vi += 256) {
        int r = vi >> 5, jc = (vi & 31) << 2;
        *(float4*)&hs[r][jc] = *(const float4*)&xres[(size_t)(r0 + r) * C + jc];
    }
    __syncthreads();
    if (t < 128) {
        int r = t >> 3, seg = t & 7;
        float s = 0.f;
        #pragma unroll
        for (int i = 0; i < 16; i++) { float xv = hs[r][seg * 16 + i]; s = fmaf(xv, xv, s); }
        red[r][seg] = s;
    }
    __syncthreads();
    if (t < R) {
        float s = 0.f;
        #pragma unroll
        for (int i = 0; i < 8; i++) s += red[t][i];
        scl[t] = rsqrtf(s * (1.0f / C) + EPSF);
    }
    __syncthreads();
    for (int vi = t; vi < 512; vi += 256) {
        int r = vi >> 5, jc = (vi & 31) << 2;
        float4 val = *(float4*)&hs[r][jc];
        float4 w4 = *(const float4*)&n2w[jc];
        float sc = scl[r];
        val.x *= sc * w4.x; val.y *= sc * w4.y; val.z *= sc * w4.z; val.w *= sc * w4.w;
        *(float4*)&hs[r][jc] = val;
    }
    __syncthreads();

    const int c = blockIdx.y * 256 + t;    // col of gate/up
    float g[R] = {}, u[R] = {};
    for (int j = 0; j < C; j++) {
        float wg = gw[j * HID + c];
        float wu = uw[j * HID + c];
        #pragma unroll
        for (int r = 0; r < R; r++) {
            float hj = hs[r][j];
            g[r] = fmaf(hj, wg, g[r]);
            u[r] = fmaf(hj, wu, u[r]);
        }
    }
    for (int r = 0; r < R; r++) {
        float sg = g[r] / (1.0f + __expf(-g[r]));
        gu[(size_t)(r0 + r) * HID + c] = sg * u[r];
    }
}

// ---------------- Kernel 5: out = xres + gu@dw  (R=16) ----------------
__global__ __launch_bounds__(256) void k_ffn2(
    const float* __restrict__ gu, const float* __restrict__ dw,
    const float* __restrict__ xres, float* __restrict__ out)
{
    __shared__ float gs[R][HID];       // 32 KB
    __shared__ float buf[2][R][C];     // 16 KB
    const int r0 = blockIdx.x * R;
    const int t = threadIdx.x;

    for (int vi = t; vi < 2048; vi += 256) {
        int r = vi >> 7, jc = (vi & 127) << 2;
        *(float4*)&gs[r][jc] = *(const float4*)&gu[(size_t)(r0 + r) * HID + jc];
    }
    __syncthreads();

    const int c = t & 127, kh = t >> 7;
    float acc[R] = {};
    for (int j = kh * 256; j < kh * 256 + 256; j++) {
        float wj = dw[j * C + c];
        #pragma unroll
        for (int r = 0; r < R; r++) acc[r] = fmaf(gs[r][j], wj, acc[r]);
    }
    #pragma unroll
    for (int r = 0; r < R; r++) buf[kh][r][c] = acc[r];
    __syncthreads();
    if (t < 128) {
        for (int r = 0; r < R; r++) {
            size_t idx = (size_t)(r0 + r) * C + t;
            out[idx] = xres[idx] + buf[0][r][t] + buf[1][r][t];
        }
    }
}

extern "C" void kernel_launch(void* const* d_in, const int* in_sizes, int n_in,
                              void* d_out, int out_size, void* d_ws, size_t ws_size,
                              hipStream_t stream)
{
    const float* x   = (const float*)d_in[0];
    const float* n1  = (const float*)d_in[1];
    const float* anw = (const float*)d_in[2];
    const float* n2  = (const float*)d_in[3];
    const float* wq  = (const float*)d_in[4];
    const float* wk  = (const float*)d_in[5];
    const float* wv  = (const float*)d_in[6];
    const float* wo  = (const float*)d_in[7];
    const float* gw  = (const float*)d_in[8];
    const float* uw  = (const float*)d_in[9];
    const float* dw  = (const float*)d_in[10];
    float* out = (float*)d_out;

    float* ws = (float*)d_ws;
    const size_t N = (size_t)NVOX * C;
    float* q    = ws;
    float* k    = ws + N;
    float* v    = ws + 2 * N;
    float* o    = ws + 3 * N;
    float* xres = ws + 4 * N;
    float* gu   = ws + 5 * N;   // NVOX*HID = 4N floats

    k_norm_qkv<<<NVOX / R, 384, 0, stream>>>(x, n1, wq, wk, wv, q, k, v);
    k_attn   <<<NVOX, 256, 0, stream>>>(q, k, v, o);
    k_attnout<<<NVOX / R, 256, 0, stream>>>(o, wo, anw, x, xres);
    dim3 g4(NVOX / R, 2);
    k_ffn1   <<<g4, 256, 0, stream>>>(xres, n2, gw, uw, gu);
    k_ffn2   <<<NVOX / R, 256, 0, stream>>>(gu, dw, xres, out);
}

// Round 4
// 105.740 us; speedup vs baseline: 1.9184x; 1.7149x over previous
//
#include <hip/hip_runtime.h>
#include <hip/hip_bf16.h>

#define NVOX 4096
#define C    128
#define HID  512
#define EPSF 1e-6f

typedef __attribute__((ext_vector_type(8))) short bf16x8;
typedef __attribute__((ext_vector_type(4))) float f32x4;

__device__ __forceinline__ short f2bs(float f) {
    __hip_bfloat16 h = __float2bfloat16(f);
    short s; __builtin_memcpy(&s, &h, 2); return s;
}
__device__ __forceinline__ float bs2f(unsigned short u) {
    return __uint_as_float(((unsigned)u) << 16);
}

// A-frag from swizzled LDS tile hs[16][128] (bf16 shorts, col ^ ((row&7)<<3))
__device__ __forceinline__ bf16x8 lda(const short* hs, int lane, int ks) {
    int r = lane & 15, g = lane >> 4;
    int col = (ks * 32 + g * 8) ^ ((r & 7) << 3);
    return *(const bf16x8*)(hs + r * 128 + col);
}

// ---------- weight prep: convert fp32 weights -> bf16 fragment-order ----------
// dst elem for (k,c) of a KxN matrix: ((ct*KS+ks)*64 + lane)*8 + j
//   ct=c>>4, ks=k>>5, lane=((k>>3)&3)*16 + (c&15), j=k&7
__global__ __launch_bounds__(256) void k_prep(
    const float* __restrict__ wq, const float* __restrict__ wk,
    const float* __restrict__ wv, const float* __restrict__ wo,
    const float* __restrict__ gw, const float* __restrict__ uw,
    const float* __restrict__ dw, short* __restrict__ wsw)
{
    int id = blockIdx.x * 256 + threadIdx.x;   // 262144 total
    const float* src; int base, k, c, N, K;
    if (id < 65536) {
        int m = id >> 14, loc = id & 16383;
        src = (m == 0) ? wq : (m == 1) ? wk : (m == 2) ? wv : wo;
        base = m << 14; N = 128; K = 128;
        k = loc >> 7; c = loc & 127;
    } else {
        int l2 = id - 65536, m = l2 >> 16, loc = l2 & 65535;
        if (m == 0)      { src = gw; base = 65536;  N = 512; K = 128; }
        else if (m == 1) { src = uw; base = 131072; N = 512; K = 128; }
        else             { src = dw; base = 196608; N = 128; K = 512; }
        k = (N == 512) ? (loc >> 9) : (loc >> 7);
        c = (N == 512) ? (loc & 511) : (loc & 127);
    }
    int KS = K >> 5;
    int ct = c >> 4, ks = k >> 5, lane = ((k >> 3) & 3) * 16 + (c & 15), j = k & 7;
    wsw[base + (((ct * KS + ks) * 64 + lane) << 3) + j] = f2bs(src[k * N + c]);
}

// ---------- K1: rmsnorm(x)*n1 -> q(f32), k(bf16), v(f32) via MFMA ----------
// grid (256, 3): y = matrix (0=q,1=k,2=v). block 256 = 4 waves, 16 rows/block.
__global__ __launch_bounds__(256) void k_qkv(
    const float* __restrict__ x, const float* __restrict__ n1,
    const short* __restrict__ wsw,
    float* __restrict__ q, short* __restrict__ kbf, float* __restrict__ v)
{
    __shared__ float xs[16][128];
    __shared__ short hs[2048];
    __shared__ float red[16][8];
    __shared__ float scl[16];
    const int r0 = blockIdx.x * 16, m = blockIdx.y, t = threadIdx.x;

    for (int vi = t; vi < 512; vi += 256) {
        int r = vi >> 5, jc = (vi & 31) << 2;
        *(float4*)&xs[r][jc] = *(const float4*)&x[(size_t)(r0 + r) * 128 + jc];
    }
    __syncthreads();
    if (t < 128) {
        int r = t >> 3, seg = t & 7; float s = 0.f;
        #pragma unroll
        for (int i = 0; i < 16; i++) { float xv = xs[r][seg * 16 + i]; s = fmaf(xv, xv, s); }
        red[r][seg] = s;
    }
    __syncthreads();
    if (t < 16) {
        float s = 0.f;
        #pragma unroll
        for (int i = 0; i < 8; i++) s += red[t][i];
        scl[t] = rsqrtf(s * (1.0f / 128.0f) + EPSF);
    }
    __syncthreads();
    for (int vi = t; vi < 2048; vi += 256) {
        int r = vi >> 7, c = vi & 127;
        hs[r * 128 + (c ^ ((r & 7) << 3))] = f2bs(xs[r][c] * scl[r] * n1[c]);
    }
    __syncthreads();

    const int w = t >> 6, lane = t & 63;
    const short* wb = wsw + (m << 14);
    f32x4 a0 = {0.f,0.f,0.f,0.f}, a1 = {0.f,0.f,0.f,0.f};
    #pragma unroll
    for (int ks = 0; ks < 4; ks++) {
        bf16x8 a = lda(hs, lane, ks);
        bf16x8 b0 = *(const bf16x8*)(wb + ((((w * 2) * 4 + ks) * 64 + lane) << 3));
        bf16x8 b1 = *(const bf16x8*)(wb + ((((w * 2 + 1) * 4 + ks) * 64 + lane) << 3));
        a0 = __builtin_amdgcn_mfma_f32_16x16x32_bf16(a, b0, a0, 0, 0, 0);
        a1 = __builtin_amdgcn_mfma_f32_16x16x32_bf16(a, b1, a1, 0, 0, 0);
    }
    int rb = (lane >> 4) * 4, cl = lane & 15, cb = w * 32;
    if (m == 1) {
        #pragma unroll
        for (int i = 0; i < 4; i++) {
            kbf[(size_t)(r0 + rb + i) * 128 + cb + cl]      = f2bs(a0[i]);
            kbf[(size_t)(r0 + rb + i) * 128 + cb + 16 + cl] = f2bs(a1[i]);
        }
    } else {
        float* outp = (m == 0) ? q : v;
        #pragma unroll
        for (int i = 0; i < 4; i++) {
            outp[(size_t)(r0 + rb + i) * 128 + cb + cl]      = a0[i];
            outp[(size_t)(r0 + rb + i) * 128 + cb + 16 + cl] = a1[i];
        }
    }
}

// ---------- K2: local-window attention; K staged in LDS (bf16, swizzled) ----------
__global__ __launch_bounds__(256) void k_attn(
    const float* __restrict__ q, const short* __restrict__ kbf,
    const float* __restrict__ v, short* __restrict__ obf)
{
    int vox = blockIdx.x;
    int w0 = vox & 15, h0 = (vox >> 4) & 15, d0 = vox >> 8;
    int t = threadIdx.x;
    int head = t >> 6, lane = t & 63;

    __shared__ short ks_l[125 * 128];
    __shared__ float qs[128];
    __shared__ float ps[4][128];
    __shared__ int   ns[128];

    if (t < 128) {
        int nv = -1;
        if (t < 125) {
            int dd = t / 25 - 2, dh = (t / 5) % 5 - 2, dw = t % 5 - 2;
            int nd = d0 + dd, nh = h0 + dh, nw_ = w0 + dw;
            if ((unsigned)nd < 16u && (unsigned)nh < 16u && (unsigned)nw_ < 16u)
                nv = (nd << 8) | (nh << 4) | nw_;
        }
        ns[t] = nv;
        qs[t] = q[vox * 128 + t];
    }
    __syncthreads();

    {   // stage K window: thread -> (row r = t>>1, 64-col half)
        int r = t >> 1, c0 = (t & 1) * 64;
        if (r < 125) {
            int nv = ns[r];
            if (nv >= 0) {
                const short* src = kbf + (size_t)nv * 128 + c0;
                int p3 = (r & 7) << 3;
                #pragma unroll
                for (int ci = 0; ci < 8; ci++) {
                    int col = (c0 + ci * 8) ^ p3;
                    *(uint4*)&ks_l[r * 128 + col] = *(const uint4*)(src + ci * 8);
                }
            }
        }
    }
    __syncthreads();

    const float inv_sqrt_hd = 0.17677669529663687f;
    float sc[2] = { -1e30f, -1e30f };
    #pragma unroll
    for (int rr = 0; rr < 2; rr++) {
        int kk = lane + 64 * rr;
        if (kk < 125 && ns[kk] >= 0) {
            int p3 = (kk & 7) << 3;
            float acc = 0.f;
            #pragma unroll
            for (int ci = 0; ci < 4; ci++) {
                int col = (head * 32 + ci * 8) ^ p3;
                uint4 raw = *(const uint4*)&ks_l[kk * 128 + col];
                const unsigned short* u = (const unsigned short*)&raw;
                #pragma unroll
                for (int j = 0; j < 8; j++)
                    acc = fmaf(qs[head * 32 + ci * 8 + j], bs2f(u[j]), acc);
            }
            sc[rr] = acc * inv_sqrt_hd;
        }
    }
    float m = fmaxf(sc[0], sc[1]);
    for (int off = 32; off; off >>= 1) m = fmaxf(m, __shfl_xor(m, off));
    float e0 = (sc[0] > -1e29f) ? __expf(sc[0] - m) : 0.f;
    float e1 = (sc[1] > -1e29f) ? __expf(sc[1] - m) : 0.f;
    float s = e0 + e1;
    for (int off = 32; off; off >>= 1) s += __shfl_xor(s, off);
    float invs = 1.0f / s;
    ps[head][lane] = e0 * invs;
    ps[head][lane + 64] = e1 * invs;
    __syncthreads();

    int e = lane & 31, half = lane >> 5;
    float acc = 0.f;
    int kk0 = half ? 64 : 0, kk1 = half ? 125 : 64;
    for (int kk = kk0; kk < kk1; kk++) {
        int nv = ns[kk];
        if (nv >= 0) acc = fmaf(ps[head][kk], v[(size_t)nv * 128 + head * 32 + e], acc);
    }
    acc += __shfl_xor(acc, 32);
    if (half == 0) obf[vox * 128 + head * 32 + e] = f2bs(acc);
}

// ---------- K3: xres = x + rmsnorm(o@wo)*anw (MFMA) ----------
__global__ __launch_bounds__(256) void k_attnout(
    const short* __restrict__ obf, const short* __restrict__ wsw,
    const float* __restrict__ anw, const float* __restrict__ x,
    float* __restrict__ xres)
{
    __shared__ float ybuf[16][132];
    __shared__ float red[16][8];
    __shared__ float scl[16];
    const int r0 = blockIdx.x * 16, t = threadIdx.x;
    const int w = t >> 6, lane = t & 63;
    const short* wb = wsw + (3 << 14);
    const int ar = lane & 15, ag = lane >> 4;

    f32x4 a0 = {0.f,0.f,0.f,0.f}, a1 = {0.f,0.f,0.f,0.f};
    #pragma unroll
    for (int ks = 0; ks < 4; ks++) {
        bf16x8 a = *(const bf16x8*)(obf + (size_t)(r0 + ar) * 128 + ks * 32 + ag * 8);
        bf16x8 b0 = *(const bf16x8*)(wb + ((((w * 2) * 4 + ks) * 64 + lane) << 3));
        bf16x8 b1 = *(const bf16x8*)(wb + ((((w * 2 + 1) * 4 + ks) * 64 + lane) << 3));
        a0 = __builtin_amdgcn_mfma_f32_16x16x32_bf16(a, b0, a0, 0, 0, 0);
        a1 = __builtin_amdgcn_mfma_f32_16x16x32_bf16(a, b1, a1, 0, 0, 0);
    }
    #pragma unroll
    for (int i = 0; i < 4; i++) {
        ybuf[ag * 4 + i][w * 32 + ar]      = a0[i];
        ybuf[ag * 4 + i][w * 32 + 16 + ar] = a1[i];
    }
    __syncthreads();
    if (t < 128) {
        int r = t >> 3, seg = t & 7; float s = 0.f;
        #pragma unroll
        for (int i = 0; i < 16; i++) { float yv = ybuf[r][seg * 16 + i]; s = fmaf(yv, yv, s); }
        red[r][seg] = s;
    }
    __syncthreads();
    if (t < 16) {
        float s = 0.f;
        #pragma unroll
        for (int i = 0; i < 8; i++) s += red[t][i];
        scl[t] = rsqrtf(s * (1.0f / 128.0f) + EPSF);
    }
    __syncthreads();
    if (t < 128) {
        float aw = anw[t];
        for (int r = 0; r < 16; r++) {
            size_t idx = (size_t)(r0 + r) * 128 + t;
            xres[idx] = x[idx] + ybuf[r][t] * scl[r] * aw;
        }
    }
}

// ---------- K4: h2=rmsnorm(xres)*n2; gu = silu(h2@gw)*(h2@uw) -> bf16 (MFMA) ----------
__global__ __launch_bounds__(256) void k_ffn1(
    const float* __restrict__ xres, const float* __restrict__ n2w,
    const short* __restrict__ wsw, short* __restrict__ gubf)
{
    __shared__ float xs[16][128];
    __shared__ short hs[2048];
    __shared__ float red[16][8];
    __shared__ float scl[16];
    const int r0 = blockIdx.x * 16, t = threadIdx.x;

    for (int vi = t; vi < 512; vi += 256) {
        int r = vi >> 5, jc = (vi & 31) << 2;
        *(float4*)&xs[r][jc] = *(const float4*)&xres[(size_t)(r0 + r) * 128 + jc];
    }
    __syncthreads();
    if (t < 128) {
        int r = t >> 3, seg = t & 7; float s = 0.f;
        #pragma unroll
        for (int i = 0; i < 16; i++) { float xv = xs[r][seg * 16 + i]; s = fmaf(xv, xv, s); }
        red[r][seg] = s;
    }
    __syncthreads();
    if (t < 16) {
        float s = 0.f;
        #pragma unroll
        for (int i = 0; i < 8; i++) s += red[t][i];
        scl[t] = rsqrtf(s * (1.0f / 128.0f) + EPSF);
    }
    __syncthreads();
    for (int vi = t; vi < 2048; vi += 256) {
        int r = vi >> 7, c = vi & 127;
        hs[r * 128 + (c ^ ((r & 7) << 3))] = f2bs(xs[r][c] * scl[r] * n2w[c]);
    }
    __syncthreads();

    const int w = t >> 6, lane = t & 63;
    const short* gwb = wsw + 65536;
    const short* uwb = wsw + 131072;
    f32x4 ag[8], au[8];
    #pragma unroll
    for (int i = 0; i < 8; i++) { ag[i] = (f32x4){0.f,0.f,0.f,0.f}; au[i] = (f32x4){0.f,0.f,0.f,0.f}; }
    #pragma unroll
    for (int ks = 0; ks < 4; ks++) {
        bf16x8 a = lda(hs, lane, ks);
        #pragma unroll
        for (int i = 0; i < 8; i++) {
            int ct = w * 8 + i;
            bf16x8 bg = *(const bf16x8*)(gwb + (((ct * 4 + ks) * 64 + lane) << 3));
            bf16x8 bu = *(const bf16x8*)(uwb + (((ct * 4 + ks) * 64 + lane) << 3));
            ag[i] = __builtin_amdgcn_mfma_f32_16x16x32_bf16(a, bg, ag[i], 0, 0, 0);
            au[i] = __builtin_amdgcn_mfma_f32_16x16x32_bf16(a, bu, au[i], 0, 0, 0);
        }
    }
    int rb = (lane >> 4) * 4, cl = lane & 15;
    #pragma unroll
    for (int i = 0; i < 8; i++) {
        int col = (w * 8 + i) * 16 + cl;
        #pragma unroll
        for (int j = 0; j < 4; j++) {
            float g = ag[i][j], u = au[i][j];
            float sg = g / (1.0f + __expf(-g));
            gubf[(size_t)(r0 + rb + j) * 512 + col] = f2bs(sg * u);
        }
    }
}

// ---------- K5: out = xres + gu@dw (MFMA, K=512) ----------
__global__ __launch_bounds__(256) void k_ffn2(
    const short* __restrict__ gubf, const short* __restrict__ wsw,
    const float* __restrict__ xres, float* __restrict__ out)
{
    const int r0 = blockIdx.x * 16, t = threadIdx.x;
    const int w = t >> 6, lane = t & 63;
    const short* db = wsw + 196608;
    const int ar = lane & 15, ag = lane >> 4;

    f32x4 a0 = {0.f,0.f,0.f,0.f}, a1 = {0.f,0.f,0.f,0.f};
    #pragma unroll
    for (int ks = 0; ks < 16; ks++) {
        bf16x8 a = *(const bf16x8*)(gubf + (size_t)(r0 + ar) * 512 + ks * 32 + ag * 8);
        bf16x8 b0 = *(const bf16x8*)(db + ((((w * 2) * 16 + ks) * 64 + lane) << 3));
        bf16x8 b1 = *(const bf16x8*)(db + ((((w * 2 + 1) * 16 + ks) * 64 + lane) << 3));
        a0 = __builtin_amdgcn_mfma_f32_16x16x32_bf16(a, b0, a0, 0, 0, 0);
        a1 = __builtin_amdgcn_mfma_f32_16x16x32_bf16(a, b1, a1, 0, 0, 0);
    }
    int rb = ag * 4, cl = ar, cb = w * 32;
    #pragma unroll
    for (int i = 0; i < 4; i++) {
        size_t i0 = (size_t)(r0 + rb + i) * 128 + cb + cl;
        out[i0] = xres[i0] + a0[i];
        size_t i1 = i0 + 16;
        out[i1] = xres[i1] + a1[i];
    }
}

extern "C" void kernel_launch(void* const* d_in, const int* in_sizes, int n_in,
                              void* d_out, int out_size, void* d_ws, size_t ws_size,
                              hipStream_t stream)
{
    const float* x   = (const float*)d_in[0];
    const float* n1  = (const float*)d_in[1];
    const float* anw = (const float*)d_in[2];
    const float* n2  = (const float*)d_in[3];
    const float* wq  = (const float*)d_in[4];
    const float* wk  = (const float*)d_in[5];
    const float* wv  = (const float*)d_in[6];
    const float* wo  = (const float*)d_in[7];
    const float* gw  = (const float*)d_in[8];
    const float* uw  = (const float*)d_in[9];
    const float* dw  = (const float*)d_in[10];
    float* out = (float*)d_out;

    float* ws = (float*)d_ws;
    float* q    = ws;
    float* v    = ws + 524288;
    float* xres = ws + 1048576;
    short* kbf  = (short*)(ws + 1572864);
    short* obf  = (short*)(ws + 1835008);
    short* gubf = (short*)(ws + 2097152);
    short* wsw  = (short*)(ws + 3145728);

    k_prep<<<1024, 256, 0, stream>>>(wq, wk, wv, wo, gw, uw, dw, wsw);
    dim3 gq(256, 3);
    k_qkv   <<<gq,   256, 0, stream>>>(x, n1, wsw, q, kbf, v);
    k_attn  <<<NVOX, 256, 0, stream>>>(q, kbf, v, obf);
    k_attnout<<<256, 256, 0, stream>>>(obf, wsw, anw, x, xres);
    k_ffn1  <<<256,  256, 0, stream>>>(xres, n2, wsw, gubf);
    k_ffn2  <<<256,  256, 0, stream>>>(gubf, wsw, xres, out);
}

// Round 5
// 46.953 us; speedup vs baseline: 4.3204x; 2.2520x over previous
//
#include <hip/hip_runtime.h>
#include <hip/hip_bf16.h>

#define NVOX 4096
#define C    128
#define HID  512
#define EPSF 1e-6f

typedef __attribute__((ext_vector_type(8))) short bf16x8;
typedef __attribute__((ext_vector_type(4))) float f32x4;

__device__ __forceinline__ short f2bs(float f) {
    __hip_bfloat16 h = __float2bfloat16(f);
    short s; __builtin_memcpy(&s, &h, 2); return s;
}
__device__ __forceinline__ float bs2f(unsigned short u) {
    return __uint_as_float(((unsigned)u) << 16);
}

// A-frag from swizzled LDS tile hs[16][128] (bf16 shorts, col ^ ((row&7)<<3))
__device__ __forceinline__ bf16x8 lda(const short* hs, int lane, int ks) {
    int r = lane & 15, g = lane >> 4;
    int col = (ks * 32 + g * 8) ^ ((r & 7) << 3);
    return *(const bf16x8*)(hs + r * 128 + col);
}

// ---------- weight prep: convert fp32 weights -> bf16 fragment-order ----------
__global__ __launch_bounds__(256) void k_prep(
    const float* __restrict__ wq, const float* __restrict__ wk,
    const float* __restrict__ wv, const float* __restrict__ wo,
    const float* __restrict__ gw, const float* __restrict__ uw,
    const float* __restrict__ dw, short* __restrict__ wsw)
{
    int id = blockIdx.x * 256 + threadIdx.x;   // 262144 total
    const float* src; int base, k, c, N, K;
    if (id < 65536) {
        int m = id >> 14, loc = id & 16383;
        src = (m == 0) ? wq : (m == 1) ? wk : (m == 2) ? wv : wo;
        base = m << 14; N = 128; K = 128;
        k = loc >> 7; c = loc & 127;
    } else {
        int l2 = id - 65536, m = l2 >> 16, loc = l2 & 65535;
        if (m == 0)      { src = gw; base = 65536;  N = 512; K = 128; }
        else if (m == 1) { src = uw; base = 131072; N = 512; K = 128; }
        else             { src = dw; base = 196608; N = 128; K = 512; }
        k = (N == 512) ? (loc >> 9) : (loc >> 7);
        c = (N == 512) ? (loc & 511) : (loc & 127);
    }
    int KS = K >> 5;
    int ct = c >> 4, ks = k >> 5, lane = ((k >> 3) & 3) * 16 + (c & 15), j = k & 7;
    wsw[base + (((ct * KS + ks) * 64 + lane) << 3) + j] = f2bs(src[k * N + c]);
}

// ---------- K1: rmsnorm(x)*n1 -> q(f32), k(bf16), v(bf16) via MFMA ----------
__global__ __launch_bounds__(256) void k_qkv(
    const float* __restrict__ x, const float* __restrict__ n1,
    const short* __restrict__ wsw,
    float* __restrict__ q, short* __restrict__ kbf, short* __restrict__ vbf)
{
    __shared__ float xs[16][128];
    __shared__ short hs[2048];
    __shared__ float red[16][8];
    __shared__ float scl[16];
    const int r0 = blockIdx.x * 16, m = blockIdx.y, t = threadIdx.x;

    for (int vi = t; vi < 512; vi += 256) {
        int r = vi >> 5, jc = (vi & 31) << 2;
        *(float4*)&xs[r][jc] = *(const float4*)&x[(size_t)(r0 + r) * 128 + jc];
    }
    __syncthreads();
    if (t < 128) {
        int r = t >> 3, seg = t & 7; float s = 0.f;
        #pragma unroll
        for (int i = 0; i < 16; i++) { float xv = xs[r][seg * 16 + i]; s = fmaf(xv, xv, s); }
        red[r][seg] = s;
    }
    __syncthreads();
    if (t < 16) {
        float s = 0.f;
        #pragma unroll
        for (int i = 0; i < 8; i++) s += red[t][i];
        scl[t] = rsqrtf(s * (1.0f / 128.0f) + EPSF);
    }
    __syncthreads();
    for (int vi = t; vi < 2048; vi += 256) {
        int r = vi >> 7, c = vi & 127;
        hs[r * 128 + (c ^ ((r & 7) << 3))] = f2bs(xs[r][c] * scl[r] * n1[c]);
    }
    __syncthreads();

    const int w = t >> 6, lane = t & 63;
    const short* wb = wsw + (m << 14);
    f32x4 a0 = {0.f,0.f,0.f,0.f}, a1 = {0.f,0.f,0.f,0.f};
    #pragma unroll
    for (int ks = 0; ks < 4; ks++) {
        bf16x8 a = lda(hs, lane, ks);
        bf16x8 b0 = *(const bf16x8*)(wb + ((((w * 2) * 4 + ks) * 64 + lane) << 3));
        bf16x8 b1 = *(const bf16x8*)(wb + ((((w * 2 + 1) * 4 + ks) * 64 + lane) << 3));
        a0 = __builtin_amdgcn_mfma_f32_16x16x32_bf16(a, b0, a0, 0, 0, 0);
        a1 = __builtin_amdgcn_mfma_f32_16x16x32_bf16(a, b1, a1, 0, 0, 0);
    }
    int rb = (lane >> 4) * 4, cl = lane & 15, cb = w * 32;
    if (m == 0) {
        #pragma unroll
        for (int i = 0; i < 4; i++) {
            q[(size_t)(r0 + rb + i) * 128 + cb + cl]      = a0[i];
            q[(size_t)(r0 + rb + i) * 128 + cb + 16 + cl] = a1[i];
        }
    } else {
        short* outp = (m == 1) ? kbf : vbf;
        #pragma unroll
        for (int i = 0; i < 4; i++) {
            outp[(size_t)(r0 + rb + i) * 128 + cb + cl]      = f2bs(a0[i]);
            outp[(size_t)(r0 + rb + i) * 128 + cb + 16 + cl] = f2bs(a1[i]);
        }
    }
}

// ---------- K2: brick-tiled local attention ----------
// block = (4x4x2 query brick, 1 head); halo 8x8x6 = 384 rows of K,V (bf16) in LDS.
// 8 lanes per query (qt = t&7), 16 window positions per lane.
__global__ __launch_bounds__(256) void k_attn(
    const float* __restrict__ q, const short* __restrict__ kbf,
    const short* __restrict__ vbf, short* __restrict__ obf)
{
    __shared__ short K_lds[384 * 40];   // rows padded to 40 shorts (80 B)
    __shared__ short V_lds[384 * 40];
    __shared__ int tab[125];

    const int b = blockIdx.x, head = blockIdx.y, t = threadIdx.x;
    const int ow = (b & 3) * 4, oh = ((b >> 2) & 3) * 4, od = (b >> 4) * 2;

    if (t < 125) {
        int dd = t / 25, rem = t % 25;
        tab[t] = dd | ((rem / 5) << 4) | ((rem % 5) << 8);
    }
    for (int row = t; row < 384; row += 256) {
        int lw = row & 7, lh = (row >> 3) & 7, ld = row >> 6;
        int gd = od - 2 + ld, gh = oh - 2 + lh, gw = ow - 2 + lw;
        uint4 kc[4], vc[4];
        if (((unsigned)gd < 16u) && ((unsigned)gh < 16u) && ((unsigned)gw < 16u)) {
            size_t off = ((size_t)(((gd << 4) | gh) << 4 | gw)) * 128 + head * 32;
            #pragma unroll
            for (int c2 = 0; c2 < 4; c2++) {
                kc[c2] = *(const uint4*)(kbf + off + c2 * 8);
                vc[c2] = *(const uint4*)(vbf + off + c2 * 8);
            }
        } else {
            #pragma unroll
            for (int c2 = 0; c2 < 4; c2++) { kc[c2] = (uint4){0,0,0,0}; vc[c2] = (uint4){0,0,0,0}; }
        }
        #pragma unroll
        for (int c2 = 0; c2 < 4; c2++) {
            *(uint4*)&K_lds[row * 40 + c2 * 8] = kc[c2];
            *(uint4*)&V_lds[row * 40 + c2 * 8] = vc[c2];
        }
    }
    __syncthreads();

    const int qi = t >> 3, qt = t & 7;
    const int qw_ = qi & 3, qh_ = (qi >> 2) & 3, qd_ = qi >> 4;
    const int gqd = od + qd_, gqh = oh + qh_, gqw = ow + qw_;
    const int gvox = (((gqd << 4) | gqh) << 4) | gqw;
    const int base = (qd_ + 2) * 64 + (qh_ + 2) * 8 + (qw_ + 2);

    float qreg[32];
    {
        const float isq = 0.17677669529663687f;   // 1/sqrt(32)
        const float* qp = q + (size_t)gvox * 128 + head * 32;
        #pragma unroll
        for (int c2 = 0; c2 < 8; c2++) {
            float4 f = *(const float4*)(qp + c2 * 4);
            qreg[c2 * 4 + 0] = f.x * isq; qreg[c2 * 4 + 1] = f.y * isq;
            qreg[c2 * 4 + 2] = f.z * isq; qreg[c2 * 4 + 3] = f.w * isq;
        }
    }

    float sc[16]; int hid[16];
    float m = -1e30f;
    const int kk0 = qt * 16;
    #pragma unroll
    for (int i = 0; i < 16; i++) {
        int kk = kk0 + i;
        float s = -1e30f; int h = 0;
        if (kk < 125) {
            int tt = tab[kk];
            int dd = (tt & 15) - 2, dh = ((tt >> 4) & 15) - 2, dw = (tt >> 8) - 2;
            if (((unsigned)(gqd + dd) < 16u) & ((unsigned)(gqh + dh) < 16u) & ((unsigned)(gqw + dw) < 16u)) {
                h = base + dd * 64 + dh * 8 + dw;
                float acc = 0.f;
                #pragma unroll
                for (int c2 = 0; c2 < 4; c2++) {
                    uint4 raw = *(const uint4*)&K_lds[h * 40 + c2 * 8];
                    const unsigned short* u = (const unsigned short*)&raw;
                    #pragma unroll
                    for (int j = 0; j < 8; j++) acc = fmaf(qreg[c2 * 8 + j], bs2f(u[j]), acc);
                }
                s = acc;
            }
        }
        sc[i] = s; hid[i] = h;
        m = fmaxf(m, s);
    }
    m = fmaxf(m, __shfl_xor(m, 1));
    m = fmaxf(m, __shfl_xor(m, 2));
    m = fmaxf(m, __shfl_xor(m, 4));
    float ssum = 0.f;
    #pragma unroll
    for (int i = 0; i < 16; i++) {
        float p = (sc[i] > -1e29f) ? __expf(sc[i] - m) : 0.f;
        sc[i] = p; ssum += p;
    }
    ssum += __shfl_xor(ssum, 1);
    ssum += __shfl_xor(ssum, 2);
    ssum += __shfl_xor(ssum, 4);
    const float inv = 1.0f / ssum;

    float acc[32];
    #pragma unroll
    for (int c2 = 0; c2 < 32; c2++) acc[c2] = 0.f;
    #pragma unroll
    for (int i = 0; i < 16; i++) {
        float p = sc[i]; int h = hid[i];
        #pragma unroll
        for (int c2 = 0; c2 < 4; c2++) {
            uint4 raw = *(const uint4*)&V_lds[h * 40 + c2 * 8];
            const unsigned short* u = (const unsigned short*)&raw;
            #pragma unroll
            for (int j = 0; j < 8; j++) acc[c2 * 8 + j] = fmaf(p, bs2f(u[j]), acc[c2 * 8 + j]);
        }
    }
    #pragma unroll
    for (int c2 = 0; c2 < 32; c2++) {
        acc[c2] += __shfl_xor(acc[c2], 1);
        acc[c2] += __shfl_xor(acc[c2], 2);
        acc[c2] += __shfl_xor(acc[c2], 4);
    }
    short o4[4];
    #pragma unroll
    for (int j = 0; j < 4; j++) o4[j] = f2bs(acc[qt * 4 + j] * inv);
    unsigned long long pk; __builtin_memcpy(&pk, o4, 8);
    *(unsigned long long*)&obf[(size_t)gvox * 128 + head * 32 + qt * 4] = pk;
}

// ---------- K3: xres = x + rmsnorm(o@wo)*anw (MFMA) ----------
__global__ __launch_bounds__(256) void k_attnout(
    const short* __restrict__ obf, const short* __restrict__ wsw,
    const float* __restrict__ anw, const float* __restrict__ x,
    float* __restrict__ xres)
{
    __shared__ float ybuf[16][132];
    __shared__ float red[16][8];
    __shared__ float scl[16];
    const int r0 = blockIdx.x * 16, t = threadIdx.x;
    const int w = t >> 6, lane = t & 63;
    const short* wb = wsw + (3 << 14);
    const int ar = lane & 15, ag = lane >> 4;

    f32x4 a0 = {0.f,0.f,0.f,0.f}, a1 = {0.f,0.f,0.f,0.f};
    #pragma unroll
    for (int ks = 0; ks < 4; ks++) {
        bf16x8 a = *(const bf16x8*)(obf + (size_t)(r0 + ar) * 128 + ks * 32 + ag * 8);
        bf16x8 b0 = *(const bf16x8*)(wb + ((((w * 2) * 4 + ks) * 64 + lane) << 3));
        bf16x8 b1 = *(const bf16x8*)(wb + ((((w * 2 + 1) * 4 + ks) * 64 + lane) << 3));
        a0 = __builtin_amdgcn_mfma_f32_16x16x32_bf16(a, b0, a0, 0, 0, 0);
        a1 = __builtin_amdgcn_mfma_f32_16x16x32_bf16(a, b1, a1, 0, 0, 0);
    }
    #pragma unroll
    for (int i = 0; i < 4; i++) {
        ybuf[ag * 4 + i][w * 32 + ar]      = a0[i];
        ybuf[ag * 4 + i][w * 32 + 16 + ar] = a1[i];
    }
    __syncthreads();
    if (t < 128) {
        int r = t >> 3, seg = t & 7; float s = 0.f;
        #pragma unroll
        for (int i = 0; i < 16; i++) { float yv = ybuf[r][seg * 16 + i]; s = fmaf(yv, yv, s); }
        red[r][seg] = s;
    }
    __syncthreads();
    if (t < 16) {
        float s = 0.f;
        #pragma unroll
        for (int i = 0; i < 8; i++) s += red[t][i];
        scl[t] = rsqrtf(s * (1.0f / 128.0f) + EPSF);
    }
    __syncthreads();
    if (t < 128) {
        float aw = anw[t];
        for (int r = 0; r < 16; r++) {
            size_t idx = (size_t)(r0 + r) * 128 + t;
            xres[idx] = x[idx] + ybuf[r][t] * scl[r] * aw;
        }
    }
}

// ---------- K4: h2=rmsnorm(xres)*n2; gu = silu(h2@gw)*(h2@uw) -> bf16 (MFMA) ----------
__global__ __launch_bounds__(256) void k_ffn1(
    const float* __restrict__ xres, const float* __restrict__ n2w,
    const short* __restrict__ wsw, short* __restrict__ gubf)
{
    __shared__ float xs[16][128];
    __shared__ short hs[2048];
    __shared__ float red[16][8];
    __shared__ float scl[16];
    const int r0 = blockIdx.x * 16, t = threadIdx.x;

    for (int vi = t; vi < 512; vi += 256) {
        int r = vi >> 5, jc = (vi & 31) << 2;
        *(float4*)&xs[r][jc] = *(const float4*)&xres[(size_t)(r0 + r) * 128 + jc];
    }
    __syncthreads();
    if (t < 128) {
        int r = t >> 3, seg = t & 7; float s = 0.f;
        #pragma unroll
        for (int i = 0; i < 16; i++) { float xv = xs[r][seg * 16 + i]; s = fmaf(xv, xv, s); }
        red[r][seg] = s;
    }
    __syncthreads();
    if (t < 16) {
        float s = 0.f;
        #pragma unroll
        for (int i = 0; i < 8; i++) s += red[t][i];
        scl[t] = rsqrtf(s * (1.0f / 128.0f) + EPSF);
    }
    __syncthreads();
    for (int vi = t; vi < 2048; vi += 256) {
        int r = vi >> 7, c = vi & 127;
        hs[r * 128 + (c ^ ((r & 7) << 3))] = f2bs(xs[r][c] * scl[r] * n2w[c]);
    }
    __syncthreads();

    const int w = t >> 6, lane = t & 63;
    const short* gwb = wsw + 65536;
    const short* uwb = wsw + 131072;
    f32x4 ag[8], au[8];
    #pragma unroll
    for (int i = 0; i < 8; i++) { ag[i] = (f32x4){0.f,0.f,0.f,0.f}; au[i] = (f32x4){0.f,0.f,0.f,0.f}; }
    #pragma unroll
    for (int ks = 0; ks < 4; ks++) {
        bf16x8 a = lda(hs, lane, ks);
        #pragma unroll
        for (int i = 0; i < 8; i++) {
            int ct = w * 8 + i;
            bf16x8 bg = *(const bf16x8*)(gwb + (((ct * 4 + ks) * 64 + lane) << 3));
            bf16x8 bu = *(const bf16x8*)(uwb + (((ct * 4 + ks) * 64 + lane) << 3));
            ag[i] = __builtin_amdgcn_mfma_f32_16x16x32_bf16(a, bg, ag[i], 0, 0, 0);
            au[i] = __builtin_amdgcn_mfma_f32_16x16x32_bf16(a, bu, au[i], 0, 0, 0);
        }
    }
    int rb = (lane >> 4) * 4, cl = lane & 15;
    #pragma unroll
    for (int i = 0; i < 8; i++) {
        int col = (w * 8 + i) * 16 + cl;
        #pragma unroll
        for (int j = 0; j < 4; j++) {
            float g = ag[i][j], u = au[i][j];
            float sg = g / (1.0f + __expf(-g));
            gubf[(size_t)(r0 + rb + j) * 512 + col] = f2bs(sg * u);
        }
    }
}

// ---------- K5: out = xres + gu@dw (MFMA, K=512) ----------
__global__ __launch_bounds__(256) void k_ffn2(
    const short* __restrict__ gubf, const short* __restrict__ wsw,
    const float* __restrict__ xres, float* __restrict__ out)
{
    const int r0 = blockIdx.x * 16, t = threadIdx.x;
    const int w = t >> 6, lane = t & 63;
    const short* db = wsw + 196608;
    const int ar = lane & 15, ag = lane >> 4;

    f32x4 a0 = {0.f,0.f,0.f,0.f}, a1 = {0.f,0.f,0.f,0.f};
    #pragma unroll
    for (int ks = 0; ks < 16; ks++) {
        bf16x8 a = *(const bf16x8*)(gubf + (size_t)(r0 + ar) * 512 + ks * 32 + ag * 8);
        bf16x8 b0 = *(const bf16x8*)(db + ((((w * 2) * 16 + ks) * 64 + lane) << 3));
        bf16x8 b1 = *(const bf16x8*)(db + ((((w * 2 + 1) * 16 + ks) * 64 + lane) << 3));
        a0 = __builtin_amdgcn_mfma_f32_16x16x32_bf16(a, b0, a0, 0, 0, 0);
        a1 = __builtin_amdgcn_mfma_f32_16x16x32_bf16(a, b1, a1, 0, 0, 0);
    }
    int rb = ag * 4, cl = ar, cb = w * 32;
    #pragma unroll
    for (int i = 0; i < 4; i++) {
        size_t i0 = (size_t)(r0 + rb + i) * 128 + cb + cl;
        out[i0] = xres[i0] + a0[i];
        size_t i1 = i0 + 16;
        out[i1] = xres[i1] + a1[i];
    }
}

extern "C" void kernel_launch(void* const* d_in, const int* in_sizes, int n_in,
                              void* d_out, int out_size, void* d_ws, size_t ws_size,
                              hipStream_t stream)
{
    const float* x   = (const float*)d_in[0];
    const float* n1  = (const float*)d_in[1];
    const float* anw = (const float*)d_in[2];
    const float* n2  = (const float*)d_in[3];
    const float* wq  = (const float*)d_in[4];
    const float* wk  = (const float*)d_in[5];
    const float* wv  = (const float*)d_in[6];
    const float* wo  = (const float*)d_in[7];
    const float* gw  = (const float*)d_in[8];
    const float* uw  = (const float*)d_in[9];
    const float* dw  = (const float*)d_in[10];
    float* out = (float*)d_out;

    float* ws = (float*)d_ws;
    float* q    = ws;                         // 524288 f
    float* xres = ws + 524288;                // 524288 f
    short* kbf  = (short*)(ws + 1048576);     // 524288 sh = 262144 f
    short* vbf  = (short*)(ws + 1310720);     // 524288 sh
    short* obf  = (short*)(ws + 1572864);     // 524288 sh
    short* gubf = (short*)(ws + 1835008);     // 2097152 sh = 1048576 f
    short* wsw  = (short*)(ws + 2883584);     // 262144 sh

    k_prep<<<1024, 256, 0, stream>>>(wq, wk, wv, wo, gw, uw, dw, wsw);
    dim3 gq(256, 3);
    k_qkv   <<<gq,   256, 0, stream>>>(x, n1, wsw, q, kbf, vbf);
    dim3 ga(128, 4);
    k_attn  <<<ga,   256, 0, stream>>>(q, kbf, vbf, obf);
    k_attnout<<<256, 256, 0, stream>>>(obf, wsw, anw, x, xres);
    k_ffn1  <<<256,  256, 0, stream>>>(xres, n2, wsw, gubf);
    k_ffn2  <<<256,  256, 0, stream>>>(gubf, wsw, xres, out);
}

// Round 6
// 42.546 us; speedup vs baseline: 4.7679x; 1.1036x over previous
//
#include <hip/hip_runtime.h>
#include <hip/hip_bf16.h>

#define NVOX 4096
#define C    128
#define HID  512
#define EPSF 1e-6f

typedef __attribute__((ext_vector_type(8))) short bf16x8;
typedef __attribute__((ext_vector_type(4))) float f32x4;

__device__ __forceinline__ short f2bs(float f) {
    __hip_bfloat16 h = __float2bfloat16(f);
    short s; __builtin_memcpy(&s, &h, 2); return s;
}
__device__ __forceinline__ float bs2f(unsigned short u) {
    return __uint_as_float(((unsigned)u) << 16);
}

// A-frag from swizzled LDS tile hs[16][128] (bf16 shorts, col ^ ((row&7)<<3))
__device__ __forceinline__ bf16x8 lda(const short* hs, int lane, int ks) {
    int r = lane & 15, g = lane >> 4;
    int col = (ks * 32 + g * 8) ^ ((r & 7) << 3);
    return *(const bf16x8*)(hs + r * 128 + col);
}

// ---------- weight prep: convert fp32 weights -> bf16 fragment-order ----------
__global__ __launch_bounds__(256) void k_prep(
    const float* __restrict__ wq, const float* __restrict__ wk,
    const float* __restrict__ wv, const float* __restrict__ wo,
    const float* __restrict__ gw, const float* __restrict__ uw,
    const float* __restrict__ dw, short* __restrict__ wsw)
{
    int id = blockIdx.x * 256 + threadIdx.x;   // 262144 total
    const float* src; int base, k, c, N, K;
    if (id < 65536) {
        int m = id >> 14, loc = id & 16383;
        src = (m == 0) ? wq : (m == 1) ? wk : (m == 2) ? wv : wo;
        base = m << 14; N = 128; K = 128;
        k = loc >> 7; c = loc & 127;
    } else {
        int l2 = id - 65536, m = l2 >> 16, loc = l2 & 65535;
        if (m == 0)      { src = gw; base = 65536;  N = 512; K = 128; }
        else if (m == 1) { src = uw; base = 131072; N = 512; K = 128; }
        else             { src = dw; base = 196608; N = 128; K = 512; }
        k = (N == 512) ? (loc >> 9) : (loc >> 7);
        c = (N == 512) ? (loc & 511) : (loc & 127);
    }
    int KS = K >> 5;
    int ct = c >> 4, ks = k >> 5, lane = ((k >> 3) & 3) * 16 + (c & 15), j = k & 7;
    wsw[base + (((ct * KS + ks) * 64 + lane) << 3) + j] = f2bs(src[k * N + c]);
}

// ---------- K1: rmsnorm(x)*n1 -> q(f32), k(bf16), v(bf16), fused ----------
__global__ __launch_bounds__(256) void k_qkv(
    const float* __restrict__ x, const float* __restrict__ n1,
    const short* __restrict__ wsw,
    float* __restrict__ q, short* __restrict__ kbf, short* __restrict__ vbf)
{
    __shared__ float xs[16][128];
    __shared__ short hs[2048];
    __shared__ float red[16][8];
    __shared__ float scl[16];
    const int r0 = blockIdx.x * 16, t = threadIdx.x;

    for (int vi = t; vi < 512; vi += 256) {
        int r = vi >> 5, jc = (vi & 31) << 2;
        *(float4*)&xs[r][jc] = *(const float4*)&x[(size_t)(r0 + r) * 128 + jc];
    }
    __syncthreads();
    if (t < 128) {
        int r = t >> 3, seg = t & 7; float s = 0.f;
        #pragma unroll
        for (int i = 0; i < 16; i++) { float xv = xs[r][seg * 16 + i]; s = fmaf(xv, xv, s); }
        red[r][seg] = s;
    }
    __syncthreads();
    if (t < 16) {
        float s = 0.f;
        #pragma unroll
        for (int i = 0; i < 8; i++) s += red[t][i];
        scl[t] = rsqrtf(s * (1.0f / 128.0f) + EPSF);
    }
    __syncthreads();
    for (int vi = t; vi < 2048; vi += 256) {
        int r = vi >> 7, c = vi & 127;
        hs[r * 128 + (c ^ ((r & 7) << 3))] = f2bs(xs[r][c] * scl[r] * n1[c]);
    }
    __syncthreads();

    const int w = t >> 6, lane = t & 63;
    bf16x8 af[4];
    #pragma unroll
    for (int ks = 0; ks < 4; ks++) af[ks] = lda(hs, lane, ks);

    const int rb = (lane >> 4) * 4, cl = lane & 15, cb = w * 32;
    #pragma unroll
    for (int m = 0; m < 3; m++) {
        const short* wb = wsw + (m << 14);
        f32x4 a0 = {0.f,0.f,0.f,0.f}, a1 = {0.f,0.f,0.f,0.f};
        #pragma unroll
        for (int ks = 0; ks < 4; ks++) {
            bf16x8 b0 = *(const bf16x8*)(wb + ((((w * 2) * 4 + ks) * 64 + lane) << 3));
            bf16x8 b1 = *(const bf16x8*)(wb + ((((w * 2 + 1) * 4 + ks) * 64 + lane) << 3));
            a0 = __builtin_amdgcn_mfma_f32_16x16x32_bf16(af[ks], b0, a0, 0, 0, 0);
            a1 = __builtin_amdgcn_mfma_f32_16x16x32_bf16(af[ks], b1, a1, 0, 0, 0);
        }
        if (m == 0) {
            #pragma unroll
            for (int i = 0; i < 4; i++) {
                q[(size_t)(r0 + rb + i) * 128 + cb + cl]      = a0[i];
                q[(size_t)(r0 + rb + i) * 128 + cb + 16 + cl] = a1[i];
            }
        } else {
            short* outp = (m == 1) ? kbf : vbf;
            #pragma unroll
            for (int i = 0; i < 4; i++) {
                outp[(size_t)(r0 + rb + i) * 128 + cb + cl]      = f2bs(a0[i]);
                outp[(size_t)(r0 + rb + i) * 128 + cb + 16 + cl] = f2bs(a1[i]);
            }
        }
    }
}

// ---------- K2: brick-tiled local attention ----------
__global__ __launch_bounds__(256) void k_attn(
    const float* __restrict__ q, const short* __restrict__ kbf,
    const short* __restrict__ vbf, short* __restrict__ obf)
{
    __shared__ short K_lds[384 * 40];
    __shared__ short V_lds[384 * 40];
    __shared__ int tab[125];

    const int b = blockIdx.x, head = blockIdx.y, t = threadIdx.x;
    const int ow = (b & 3) * 4, oh = ((b >> 2) & 3) * 4, od = (b >> 4) * 2;

    if (t < 125) {
        int dd = t / 25, rem = t % 25;
        tab[t] = dd | ((rem / 5) << 4) | ((rem % 5) << 8);
    }
    for (int row = t; row < 384; row += 256) {
        int lw = row & 7, lh = (row >> 3) & 7, ld = row >> 6;
        int gd = od - 2 + ld, gh = oh - 2 + lh, gw = ow - 2 + lw;
        uint4 kc[4], vc[4];
        if (((unsigned)gd < 16u) && ((unsigned)gh < 16u) && ((unsigned)gw < 16u)) {
            size_t off = ((size_t)(((gd << 4) | gh) << 4 | gw)) * 128 + head * 32;
            #pragma unroll
            for (int c2 = 0; c2 < 4; c2++) {
                kc[c2] = *(const uint4*)(kbf + off + c2 * 8);
                vc[c2] = *(const uint4*)(vbf + off + c2 * 8);
            }
        } else {
            #pragma unroll
            for (int c2 = 0; c2 < 4; c2++) { kc[c2] = (uint4){0,0,0,0}; vc[c2] = (uint4){0,0,0,0}; }
        }
        #pragma unroll
        for (int c2 = 0; c2 < 4; c2++) {
            *(uint4*)&K_lds[row * 40 + c2 * 8] = kc[c2];
            *(uint4*)&V_lds[row * 40 + c2 * 8] = vc[c2];
        }
    }
    __syncthreads();

    const int qi = t >> 3, qt = t & 7;
    const int qw_ = qi & 3, qh_ = (qi >> 2) & 3, qd_ = qi >> 4;
    const int gqd = od + qd_, gqh = oh + qh_, gqw = ow + qw_;
    const int gvox = (((gqd << 4) | gqh) << 4) | gqw;
    const int base = (qd_ + 2) * 64 + (qh_ + 2) * 8 + (qw_ + 2);

    float qreg[32];
    {
        const float isq = 0.17677669529663687f;
        const float* qp = q + (size_t)gvox * 128 + head * 32;
        #pragma unroll
        for (int c2 = 0; c2 < 8; c2++) {
            float4 f = *(const float4*)(qp + c2 * 4);
            qreg[c2 * 4 + 0] = f.x * isq; qreg[c2 * 4 + 1] = f.y * isq;
            qreg[c2 * 4 + 2] = f.z * isq; qreg[c2 * 4 + 3] = f.w * isq;
        }
    }

    float sc[16]; int hid[16];
    float m = -1e30f;
    const int kk0 = qt * 16;
    #pragma unroll
    for (int i = 0; i < 16; i++) {
        int kk = kk0 + i;
        float s = -1e30f; int h = 0;
        if (kk < 125) {
            int tt = tab[kk];
            int dd = (tt & 15) - 2, dh = ((tt >> 4) & 15) - 2, dw = (tt >> 8) - 2;
            if (((unsigned)(gqd + dd) < 16u) & ((unsigned)(gqh + dh) < 16u) & ((unsigned)(gqw + dw) < 16u)) {
                h = base + dd * 64 + dh * 8 + dw;
                float acc = 0.f;
                #pragma unroll
                for (int c2 = 0; c2 < 4; c2++) {
                    uint4 raw = *(const uint4*)&K_lds[h * 40 + c2 * 8];
                    const unsigned short* u = (const unsigned short*)&raw;
                    #pragma unroll
                    for (int j = 0; j < 8; j++) acc = fmaf(qreg[c2 * 8 + j], bs2f(u[j]), acc);
                }
                s = acc;
            }
        }
        sc[i] = s; hid[i] = h;
        m = fmaxf(m, s);
    }
    m = fmaxf(m, __shfl_xor(m, 1));
    m = fmaxf(m, __shfl_xor(m, 2));
    m = fmaxf(m, __shfl_xor(m, 4));
    float ssum = 0.f;
    #pragma unroll
    for (int i = 0; i < 16; i++) {
        float p = (sc[i] > -1e29f) ? __expf(sc[i] - m) : 0.f;
        sc[i] = p; ssum += p;
    }
    ssum += __shfl_xor(ssum, 1);
    ssum += __shfl_xor(ssum, 2);
    ssum += __shfl_xor(ssum, 4);
    const float inv = 1.0f / ssum;

    float acc[32];
    #pragma unroll
    for (int c2 = 0; c2 < 32; c2++) acc[c2] = 0.f;
    #pragma unroll
    for (int i = 0; i < 16; i++) {
        float p = sc[i]; int h = hid[i];
        #pragma unroll
        for (int c2 = 0; c2 < 4; c2++) {
            uint4 raw = *(const uint4*)&V_lds[h * 40 + c2 * 8];
            const unsigned short* u = (const unsigned short*)&raw;
            #pragma unroll
            for (int j = 0; j < 8; j++) acc[c2 * 8 + j] = fmaf(p, bs2f(u[j]), acc[c2 * 8 + j]);
        }
    }
    #pragma unroll
    for (int c2 = 0; c2 < 32; c2++) {
        acc[c2] += __shfl_xor(acc[c2], 1);
        acc[c2] += __shfl_xor(acc[c2], 2);
        acc[c2] += __shfl_xor(acc[c2], 4);
    }
    short o4[4];
    #pragma unroll
    for (int j = 0; j < 4; j++) o4[j] = f2bs(acc[qt * 4 + j] * inv);
    unsigned long long pk; __builtin_memcpy(&pk, o4, 8);
    *(unsigned long long*)&obf[(size_t)gvox * 128 + head * 32 + qt * 4] = pk;
}

// ---------- K3: fused post-chain: attnout + ffn1 + ffn2 (LDS-resident) ----------
__global__ __launch_bounds__(256) void k_post(
    const short* __restrict__ obf, const short* __restrict__ wsw,
    const float* __restrict__ anw, const float* __restrict__ x,
    const float* __restrict__ n2w, float* __restrict__ out)
{
    __shared__ float ybuf[16][132];
    __shared__ float xres[16][128];
    __shared__ short hs[2048];
    __shared__ short gu[16 * 512];
    __shared__ float red[16][8];
    __shared__ float scl[16];

    const int r0 = blockIdx.x * 16, t = threadIdx.x;
    const int w = t >> 6, lane = t & 63;
    const int ar = lane & 15, ag_ = lane >> 4;

    // phase 1: y = o @ wo
    {
        const short* wb = wsw + (3 << 14);
        f32x4 a0 = {0.f,0.f,0.f,0.f}, a1 = {0.f,0.f,0.f,0.f};
        #pragma unroll
        for (int ks = 0; ks < 4; ks++) {
            bf16x8 a = *(const bf16x8*)(obf + (size_t)(r0 + ar) * 128 + ks * 32 + ag_ * 8);
            bf16x8 b0 = *(const bf16x8*)(wb + ((((w * 2) * 4 + ks) * 64 + lane) << 3));
            bf16x8 b1 = *(const bf16x8*)(wb + ((((w * 2 + 1) * 4 + ks) * 64 + lane) << 3));
            a0 = __builtin_amdgcn_mfma_f32_16x16x32_bf16(a, b0, a0, 0, 0, 0);
            a1 = __builtin_amdgcn_mfma_f32_16x16x32_bf16(a, b1, a1, 0, 0, 0);
        }
        #pragma unroll
        for (int i = 0; i < 4; i++) {
            ybuf[ag_ * 4 + i][w * 32 + ar]      = a0[i];
            ybuf[ag_ * 4 + i][w * 32 + 16 + ar] = a1[i];
        }
    }
    __syncthreads();

    // phase 2: xres = x + rmsnorm(y)*anw
    if (t < 128) {
        int r = t >> 3, seg = t & 7; float s = 0.f;
        #pragma unroll
        for (int i = 0; i < 16; i++) { float yv = ybuf[r][seg * 16 + i]; s = fmaf(yv, yv, s); }
        red[r][seg] = s;
    }
    __syncthreads();
    if (t < 16) {
        float s = 0.f;
        #pragma unroll
        for (int i = 0; i < 8; i++) s += red[t][i];
        scl[t] = rsqrtf(s * (1.0f / 128.0f) + EPSF);
    }
    __syncthreads();
    for (int vi = t; vi < 512; vi += 256) {
        int r = vi >> 5, jc = (vi & 31) << 2;
        float4 xv = *(const float4*)&x[(size_t)(r0 + r) * 128 + jc];
        float4 aw = *(const float4*)&anw[jc];
        float sc2 = scl[r];
        float4 o;
        o.x = xv.x + ybuf[r][jc + 0] * sc2 * aw.x;
        o.y = xv.y + ybuf[r][jc + 1] * sc2 * aw.y;
        o.z = xv.z + ybuf[r][jc + 2] * sc2 * aw.z;
        o.w = xv.w + ybuf[r][jc + 3] * sc2 * aw.w;
        *(float4*)&xres[r][jc] = o;
    }
    __syncthreads();

    // phase 3: h2 = rmsnorm(xres)*n2w -> hs
    if (t < 128) {
        int r = t >> 3, seg = t & 7; float s = 0.f;
        #pragma unroll
        for (int i = 0; i < 16; i++) { float xv = xres[r][seg * 16 + i]; s = fmaf(xv, xv, s); }
        red[r][seg] = s;
    }
    __syncthreads();
    if (t < 16) {
        float s = 0.f;
        #pragma unroll
        for (int i = 0; i < 8; i++) s += red[t][i];
        scl[t] = rsqrtf(s * (1.0f / 128.0f) + EPSF);
    }
    __syncthreads();
    for (int vi = t; vi < 2048; vi += 256) {
        int r = vi >> 7, c = vi & 127;
        hs[r * 128 + (c ^ ((r & 7) << 3))] = f2bs(xres[r][c] * scl[r] * n2w[c]);
    }
    __syncthreads();

    // phase 4: gu = silu(h2@gw)*(h2@uw)
    {
        const short* gwb = wsw + 65536;
        const short* uwb = wsw + 131072;
        bf16x8 af[4];
        #pragma unroll
        for (int ks = 0; ks < 4; ks++) af[ks] = lda(hs, lane, ks);
        f32x4 ag[8], au[8];
        #pragma unroll
        for (int i = 0; i < 8; i++) { ag[i] = (f32x4){0.f,0.f,0.f,0.f}; au[i] = (f32x4){0.f,0.f,0.f,0.f}; }
        #pragma unroll
        for (int ks = 0; ks < 4; ks++) {
            #pragma unroll
            for (int i = 0; i < 8; i++) {
                int ct = w * 8 + i;
                bf16x8 bg = *(const bf16x8*)(gwb + (((ct * 4 + ks) * 64 + lane) << 3));
                bf16x8 bu = *(const bf16x8*)(uwb + (((ct * 4 + ks) * 64 + lane) << 3));
                ag[i] = __builtin_amdgcn_mfma_f32_16x16x32_bf16(af[ks], bg, ag[i], 0, 0, 0);
                au[i] = __builtin_amdgcn_mfma_f32_16x16x32_bf16(af[ks], bu, au[i], 0, 0, 0);
            }
        }
        #pragma unroll
        for (int i = 0; i < 8; i++) {
            int col = (w * 8 + i) * 16 + ar;
            #pragma unroll
            for (int j = 0; j < 4; j++) {
                int row = ag_ * 4 + j;
                float g = ag[i][j], u = au[i][j];
                float sg = g / (1.0f + __expf(-g));
                gu[row * 512 + (col ^ ((row & 7) << 3))] = f2bs(sg * u);
            }
        }
    }
    __syncthreads();

    // phase 5: out = xres + gu @ dw
    {
        const short* db = wsw + 196608;
        f32x4 a0 = {0.f,0.f,0.f,0.f}, a1 = {0.f,0.f,0.f,0.f};
        #pragma unroll
        for (int ks = 0; ks < 16; ks++) {
            int col = (ks * 32 + ag_ * 8) ^ ((ar & 7) << 3);
            bf16x8 a = *(const bf16x8*)(gu + ar * 512 + col);
            bf16x8 b0 = *(const bf16x8*)(db + ((((w * 2) * 16 + ks) * 64 + lane) << 3));
            bf16x8 b1 = *(const bf16x8*)(db + ((((w * 2 + 1) * 16 + ks) * 64 + lane) << 3));
            a0 = __builtin_amdgcn_mfma_f32_16x16x32_bf16(a, b0, a0, 0, 0, 0);
            a1 = __builtin_amdgcn_mfma_f32_16x16x32_bf16(a, b1, a1, 0, 0, 0);
        }
        #pragma unroll
        for (int i = 0; i < 4; i++) {
            int row = ag_ * 4 + i;
            size_t i0 = (size_t)(r0 + row) * 128 + w * 32 + ar;
            out[i0]      = xres[row][w * 32 + ar]      + a0[i];
            out[i0 + 16] = xres[row][w * 32 + 16 + ar] + a1[i];
        }
    }
}

extern "C" void kernel_launch(void* const* d_in, const int* in_sizes, int n_in,
                              void* d_out, int out_size, void* d_ws, size_t ws_size,
                              hipStream_t stream)
{
    const float* x   = (const float*)d_in[0];
    const float* n1  = (const float*)d_in[1];
    const float* anw = (const float*)d_in[2];
    const float* n2  = (const float*)d_in[3];
    const float* wq  = (const float*)d_in[4];
    const float* wk  = (const float*)d_in[5];
    const float* wv  = (const float*)d_in[6];
    const float* wo  = (const float*)d_in[7];
    const float* gw  = (const float*)d_in[8];
    const float* uw  = (const float*)d_in[9];
    const float* dw  = (const float*)d_in[10];
    float* out = (float*)d_out;

    float* ws = (float*)d_ws;
    float* q    = ws;                         // 524288 f
    short* kbf  = (short*)(ws + 524288);
    short* vbf  = (short*)(ws + 786432);
    short* obf  = (short*)(ws + 1048576);
    short* wsw  = (short*)(ws + 1310720);

    k_prep<<<1024, 256, 0, stream>>>(wq, wk, wv, wo, gw, uw, dw, wsw);
    k_qkv <<<256,  256, 0, stream>>>(x, n1, wsw, q, kbf, vbf);
    dim3 ga(128, 4);
    k_attn<<<ga,   256, 0, stream>>>(q, kbf, vbf, obf);
    k_post<<<256,  256, 0, stream>>>(obf, wsw, anw, x, n2, out);
}